// Round 1
// baseline (397.012 us; speedup 1.0000x reference)
//
#include <hip/hip_runtime.h>
#include <math.h>

// GCN is linear: out = (((z3^T X) W1 + s2 b1) W2 + s1 b2) W3 + N b3) / sqrt(N)
// z_{l+1} = M^T z_l via gather over slot rows keyed by src; p_l = dinv.*z_l.
// Inherited laws (r7-r12 of prior session):
//   (1) random-address device atomics ~21 G/s (stores ride free)
//   (2) same-address atomics ~13 ns each, serialized
//   (3) in-kernel device-scope fences poison resident L2 -> kernel boundary
//       is the only cheap device-wide sync
//   (4) random 4B L2 gathers ~free   (5) ~3.5 us per dispatch boundary
//   (6) micro-restructurings of the latency-class kernels regress
// ROUND 14 (this session): two structural changes.
//   a) k_hist: deg histogram moved OFF the atomic fabric. Blocks [0,NR) own
//      disjoint 6400-bin ranges in LDS, scan all dst, plain-store deg out.
//      Slot build keeps its 600k returning atomics -> predicted ~31 us.
//   b) k_wsum fused into layer-3 qfin (k_qfin3w): block b already holds z3
//      for rows [256b,256b+256) -> per-block X reduction, one less boundary,
//      X stream overlaps gather stalls. z3 global store dropped (dead).

#define TPB 256
#define KSLOT 64
#define RBINS 6400   // bins per histogram block -> 25.6KB LDS

__device__ __forceinline__ float dinv_of(int degv) {
    return (float)(1.0 / sqrt((double)degv + 1.0));
}

// Heterogeneous dispatch:
//   blocks [0,NR): private LDS histogram of dst over bin range
//                  [b*RBINS,(b+1)*RBINS) -> plain stores to deg (disjoint).
//   blocks [NR,..): slot build, ONE returning atomic per edge.
__global__ void k_hist(const int* __restrict__ src, const int* __restrict__ dst,
                       int* __restrict__ cnt, int* __restrict__ deg,
                       int* __restrict__ slots, int E, int N, int NR) {
    if (blockIdx.x < NR) {
        __shared__ int h[RBINS];
        int lo = blockIdx.x * RBINS;
        for (int k = threadIdx.x; k < RBINS; k += TPB) h[k] = 0;
        __syncthreads();
        if ((E & 3) == 0) {                       // dst 16B-aligned (ei + E ints)
            int E4 = E >> 2;
            const int4* d4p = (const int4*)dst;
            for (int j = threadIdx.x; j < E4; j += TPB) {
                int4 d4 = d4p[j];
                int a;
                a = d4.x - lo; if ((unsigned)a < RBINS) atomicAdd(&h[a], 1);
                a = d4.y - lo; if ((unsigned)a < RBINS) atomicAdd(&h[a], 1);
                a = d4.z - lo; if ((unsigned)a < RBINS) atomicAdd(&h[a], 1);
                a = d4.w - lo; if ((unsigned)a < RBINS) atomicAdd(&h[a], 1);
            }
        } else {
            for (int j = threadIdx.x; j < E; j += TPB) {
                int a = dst[j] - lo; if ((unsigned)a < RBINS) atomicAdd(&h[a], 1);
            }
        }
        __syncthreads();
        for (int k = threadIdx.x; k < RBINS && lo + k < N; k += TPB)
            deg[lo + k] = h[k];
    } else {
        int e = (blockIdx.x - NR) * TPB + threadIdx.x;
        if (e < E) {
            int s = src[e], d = dst[e];
            int r = atomicAdd(&cnt[s], 1);
            if (r < KSLOT) slots[(size_t)s * KSLOT + r] = d;
        }
    }
}

// One propagation layer (1 thread/node, proven r8/r11 form):
//   q      = sum_{r<cnt[i]} pin[slots[i*K+r]]   (pin==null => dinv_of(deg[j]))
//   z[i]   = dinv*(q + dinv*zprev)              (first => zprev=1, else z[i])
//   p_out  = dinv*z[i]  (if p_out)  ;  *sig += sum(z)  (if sig)
__global__ void k_qfin(const int* __restrict__ deg, const int* __restrict__ cnt,
                       const int* __restrict__ slots, const float* __restrict__ pin,
                       float* __restrict__ z, float* __restrict__ p_out,
                       float* __restrict__ sig, int first, int N) {
    __shared__ float red[TPB];
    int i = blockIdx.x * blockDim.x + threadIdx.x;
    float zv = 0.0f;
    if (i < N) {
        int c = cnt[i];
        if (c > KSLOT) c = KSLOT;
        const int* row = slots + (size_t)i * KSLOT;
        float q = 0.0f;
        for (int r = 0; r < c; r += 4) {          // row is 16B-aligned; reads
            int4 s4 = *(const int4*)(row + r);    // past c stay inside the row
            if (r + 0 < c) q += pin ? pin[s4.x] : dinv_of(deg[s4.x]);
            if (r + 1 < c) q += pin ? pin[s4.y] : dinv_of(deg[s4.y]);
            if (r + 2 < c) q += pin ? pin[s4.z] : dinv_of(deg[s4.z]);
            if (r + 3 < c) q += pin ? pin[s4.w] : dinv_of(deg[s4.w]);
        }
        float dv = dinv_of(deg[i]);
        float zprev = first ? 1.0f : z[i];
        zv = dv * (q + dv * zprev);
        z[i] = zv;
        if (p_out) p_out[i] = dv * zv;
    }
    if (sig) {
        red[threadIdx.x] = zv;
        __syncthreads();
        for (int s = TPB / 2; s > 0; s >>= 1) {
            if (threadIdx.x < s) red[threadIdx.x] += red[threadIdx.x + s];
            __syncthreads();
        }
        if (threadIdx.x == 0) unsafeAtomicAdd(sig, red[0]);
    }
}

// Layer 3 fused with the X reduction: block b computes z3 for its 256 rows
// (same gather form as k_qfin, zprev = z2 in place, z3 store dropped — dead),
// then partials[b][0:128] = sum_{r in block} z3[r] * X[r][0:128].
__global__ void k_qfin3w(const int* __restrict__ deg, const int* __restrict__ cnt,
                         const int* __restrict__ slots, const float* __restrict__ pin,
                         const float* __restrict__ z, const float* __restrict__ x,
                         float* __restrict__ partials, int N) {
    __shared__ float zbuf[TPB];
    __shared__ float4 red4[TPB];
    int tid = threadIdx.x;
    int i = blockIdx.x * blockDim.x + tid;
    float zv = 0.0f;
    if (i < N) {
        int c = cnt[i];
        if (c > KSLOT) c = KSLOT;
        const int* row = slots + (size_t)i * KSLOT;
        float q = 0.0f;
        for (int r = 0; r < c; r += 4) {
            int4 s4 = *(const int4*)(row + r);
            if (r + 0 < c) q += pin[s4.x];
            if (r + 1 < c) q += pin[s4.y];
            if (r + 2 < c) q += pin[s4.z];
            if (r + 3 < c) q += pin[s4.w];
        }
        float dv = dinv_of(deg[i]);
        zv = dv * (q + dv * z[i]);
    }
    zbuf[tid] = zv;
    __syncthreads();
    // X phase: rows [base, base+nrows), perfectly coalesced, block-local.
    int base = blockIdx.x * TPB;
    int nrows = N - base; if (nrows > TPB) nrows = TPB;
    int c4 = (tid & 31) * 4;
    int rg = tid >> 5;                            // 8 row-groups
    float4 acc = make_float4(0.f, 0.f, 0.f, 0.f);
    for (int r = rg; r < nrows; r += 8) {
        float zr = zbuf[r];
        const float4 xv = *(const float4*)(x + (size_t)(base + r) * 128 + c4);
        acc.x += zr * xv.x; acc.y += zr * xv.y;
        acc.z += zr * xv.z; acc.w += zr * xv.w;
    }
    red4[tid] = acc;
    __syncthreads();
    if (tid < 32) {
        float4 a = red4[tid];
        #pragma unroll
        for (int g = 1; g < 8; ++g) {
            float4 b = red4[tid + 32 * g];
            a.x += b.x; a.y += b.y; a.z += b.z; a.w += b.w;
        }
        float* pp = partials + (size_t)blockIdx.x * 128 + c4;
        pp[0] = a.x; pp[1] = a.y; pp[2] = a.z; pp[3] = a.w;
    }
}

// 1024 threads: reduce partials -> u0, then 3-layer 128-wide chain.
__global__ __launch_bounds__(1024) void k_final(
        const float* __restrict__ partials, int nb,
        const float* __restrict__ Ws, const float* __restrict__ bs,
        const float* __restrict__ sig, float* __restrict__ out, int N) {
    __shared__ float uv[128];
    __shared__ float red[1024];
    int t = threadIdx.x;
    int j = t & 127, g = t >> 7;            // g in [0,8)
    float acc = 0.0f;
    for (int b = g; b < nb; b += 8) acc += partials[(size_t)b * 128 + j];
    red[t] = acc;
    __syncthreads();
    if (t < 128) {
        float s = 0.0f;
        #pragma unroll
        for (int gg = 0; gg < 8; ++gg) s += red[t + 128 * gg];
        uv[t] = s;
    }
    __syncthreads();
    float s1 = sig[0], s2 = sig[1];
    for (int l = 0; l < 3; ++l) {
        const float* W = Ws + (size_t)l * 16384;
        float a = 0.0f;
        #pragma unroll
        for (int kk = 0; kk < 16; ++kk) {
            int k = g * 16 + kk;
            a += uv[k] * W[k * 128 + j];
        }
        red[t] = a;
        __syncthreads();
        float nv = 0.0f;
        if (t < 128) {
            float s = 0.0f;
            #pragma unroll
            for (int gg = 0; gg < 8; ++gg) s += red[t + 128 * gg];
            float coef = (l == 0) ? s2 : (l == 1) ? s1 : (float)N;
            nv = s + coef * bs[l * 128 + t];
        }
        __syncthreads();
        if (t < 128) uv[t] = nv;
        __syncthreads();
    }
    if (t < 128) out[t] = uv[t] * (float)(1.0 / sqrt((double)N));
}

extern "C" void kernel_launch(void* const* d_in, const int* in_sizes, int n_in,
                              void* d_out, int out_size, void* d_ws, size_t ws_size,
                              hipStream_t stream) {
    const int*   ei = (const int*)d_in[0];
    const float* X  = (const float*)d_in[1];
    const float* Ws = (const float*)d_in[2];
    const float* bs = (const float*)d_in[3];
    float* out = (float*)d_out;

    int E = in_sizes[0] / 2;
    int N = in_sizes[1] / 128;
    const int* src = ei;
    const int* dst = ei + E;

    int gE = (E + TPB - 1) / TPB;
    int gN = (N + TPB - 1) / TPB;
    int NR = (N + RBINS - 1) / RBINS;       // histogram blocks (16 @ N=100k)

    // layout (floats): [cnt N][sig 4][deg N][z N][pa N][pb N]
    //                  [partials gN*128][slots N*KSLOT (16B-aligned)]
    float* ws       = (float*)d_ws;
    int*   cnt      = (int*)ws;                  // [N] memset 0
    float* sig      = ws + N;                    // [4] memset 0
    int*   deg      = (int*)ws + N + 4;          // [N] plain-stored by k_hist
    float* z        = ws + 2 * N + 4;            // [N] z1 -> z2 in place
    float* pa       = z + N;                     // [N] p1
    float* pb       = pa + N;                    // [N] p2
    float* partials = pb + N;                    // [gN*128]
    size_t so = ((size_t)(5 * (size_t)N + 4) + (size_t)gN * 128 + 3) & ~(size_t)3;
    int*   slots    = (int*)(ws + so);           // [N*KSLOT]

    hipMemsetAsync(d_ws, 0, (size_t)(N + 4) * sizeof(float), stream);

    k_hist <<<NR + gE, TPB, 0, stream>>>(src, dst, cnt, deg, slots, E, N, NR);
    // layer 1: pin = dinv on the fly (z0 = 1); sig[0] = sum z1
    k_qfin <<<gN, TPB, 0, stream>>>(deg, cnt, slots, nullptr, z, pa, &sig[0], 1, N);
    // layer 2: pin = p1, zprev = z1 in place; sig[1] = sum z2
    k_qfin <<<gN, TPB, 0, stream>>>(deg, cnt, slots, pa, z, pb, &sig[1], 0, N);
    // layer 3 fused with X reduction (z3 never materialized)
    k_qfin3w<<<gN, TPB, 0, stream>>>(deg, cnt, slots, pb, z, X, partials, N);
    k_final <<<1, 1024, 0, stream>>>(partials, gN, Ws, bs, sig, out, N);
}

// Round 2
// 197.864 us; speedup vs baseline: 2.0065x; 2.0065x over previous
//
#include <hip/hip_runtime.h>
#include <math.h>

// GCN is linear: out = (((z3^T X) W1 + s2 b1) W2 + s1 b2) W3 + N b3) / sqrt(N)
// z_{l+1} = M^T z_l via gather over slot rows keyed by src; p_l = dinv.*z_l.
// Inherited laws (r7-r12 of prior session):
//   (1) random-address device atomics ~21 G/s (stores ride free)
//   (2) same-address atomics ~13 ns each, serialized
//   (3) in-kernel device-scope fences poison resident L2 -> kernel boundary
//       is the only cheap device-wide sync
//   (4) random 4B L2 gathers ~free   (5) ~3.5 us per dispatch boundary
//   (6) micro-restructurings of the latency-class kernels regress
// ROUND 15 (this session):
//   r14 post-mortem: 16 full-scan histogram blocks on 16 CUs = 220 us serial
//   tail (424 ns/int4-iter, zero MLP from conditional LDS atomic after each
//   load; 25.6KB LDS charged to every block). Fix: 2-D decomposition.
//   a) k_hist: slot build unchanged (600k returning atomics). deg histogram
//      = NR(25) ranges x C(8) edge-chunks = 200 blocks, each scans 75k edges
//      with 8-deep batched int4 loads (MLP), 16KB LDS bins, plain-stores a
//      disjoint per-chunk partial-deg slice. Zero global atomics for deg.
//   b) k_merge: dinvf[i] = rsqrt(sum_c pdeg[c][i] + 1). Also deletes the
//      600k inline double-sqrts from layer-1's gather (now gathers dinvf).
//   c) keep r14's k_qfin3w fusion (neutral on time, -1 dispatch, z3 dead).

#define TPB 256
#define KSLOT 64
#define RBINS 4096     // bins per histogram block -> 16KB LDS (no occ. hit)
#define HCHUNKS 8      // edge chunks; pdeg partials = HCHUNKS*N ints (3.2MB)

__device__ __forceinline__ float dinv_of(int degv) {
    return (float)(1.0 / sqrt((double)degv + 1.0));
}

// Heterogeneous dispatch:
//   blocks [0,NH):  NH = NR*HCHUNKS histogram blocks. Block = (range r,
//                   chunk c): LDS-histogram chunk c of dst into bins
//                   [r*RBINS,(r+1)*RBINS), plain-store to pdeg[c][...].
//   blocks [NH,..): slot build, ONE returning atomic per edge.
__global__ void k_hist(const int* __restrict__ src, const int* __restrict__ dst,
                       int* __restrict__ cnt, int* __restrict__ pdeg,
                       int* __restrict__ slots, int E, int N, int NH) {
    __shared__ int h[RBINS];
    if (blockIdx.x < NH) {
        int r = blockIdx.x / HCHUNKS;
        int c = blockIdx.x % HCHUNKS;
        int lo = r * RBINS;
        for (int k = threadIdx.x; k < RBINS; k += TPB) h[k] = 0;
        __syncthreads();
        int EC = ((E + HCHUNKS - 1) / HCHUNKS + 3) & ~3;   // 16B-aligned chunks
        int e0 = c * EC;
        int e1 = e0 + EC; if (e1 > E) e1 = E;
        if (e0 < e1) {
            int n4 = (e1 - e0) >> 2;
            const int4* p = (const int4*)(dst + e0);
            int j = threadIdx.x;
            // main: 8 loads in flight before any LDS op (MLP against L2/HBM)
            for (; j + 7 * TPB < n4; j += 8 * TPB) {
                int4 v[8];
                #pragma unroll
                for (int u = 0; u < 8; ++u) v[u] = p[j + u * TPB];
                #pragma unroll
                for (int u = 0; u < 8; ++u) {
                    int a;
                    a = v[u].x - lo; if ((unsigned)a < RBINS) atomicAdd(&h[a], 1);
                    a = v[u].y - lo; if ((unsigned)a < RBINS) atomicAdd(&h[a], 1);
                    a = v[u].z - lo; if ((unsigned)a < RBINS) atomicAdd(&h[a], 1);
                    a = v[u].w - lo; if ((unsigned)a < RBINS) atomicAdd(&h[a], 1);
                }
            }
            for (; j < n4; j += TPB) {
                int4 v = p[j];
                int a;
                a = v.x - lo; if ((unsigned)a < RBINS) atomicAdd(&h[a], 1);
                a = v.y - lo; if ((unsigned)a < RBINS) atomicAdd(&h[a], 1);
                a = v.z - lo; if ((unsigned)a < RBINS) atomicAdd(&h[a], 1);
                a = v.w - lo; if ((unsigned)a < RBINS) atomicAdd(&h[a], 1);
            }
            int tb = e0 + (n4 << 2);
            for (int t = tb + threadIdx.x; t < e1; t += TPB) {
                int a = dst[t] - lo; if ((unsigned)a < RBINS) atomicAdd(&h[a], 1);
            }
        }
        __syncthreads();
        for (int k = threadIdx.x; k < RBINS; k += TPB) {
            int g = lo + k;
            if (g < N) pdeg[(size_t)c * N + g] = h[k];
        }
    } else {
        int e = (blockIdx.x - NH) * TPB + threadIdx.x;
        if (e < E) {
            int s = src[e], d = dst[e];
            int rr = atomicAdd(&cnt[s], 1);
            if (rr < KSLOT) slots[(size_t)s * KSLOT + rr] = d;
        }
    }
}

// dinvf[i] = 1/sqrt(deg[i]+1), deg = sum of per-chunk partials. Coalesced.
__global__ void k_merge(const int* __restrict__ pdeg, float* __restrict__ dinvf,
                        int N) {
    int i = blockIdx.x * blockDim.x + threadIdx.x;
    if (i < N) {
        int s = 0;
        #pragma unroll
        for (int c = 0; c < HCHUNKS; ++c) s += pdeg[(size_t)c * N + i];
        dinvf[i] = dinv_of(s);
    }
}

// One propagation layer (1 thread/node, proven r8/r11 form):
//   q      = sum_{r<cnt[i]} pin[slots[i*K+r]]   (layer 1: pin = dinvf)
//   z[i]   = dinv*(q + dinv*zprev)              (first => zprev=1, else z[i])
//   p_out  = dinv*z[i]  (if p_out)  ;  *sig += sum(z)  (if sig)
__global__ void k_qfin(const float* __restrict__ dinvf, const int* __restrict__ cnt,
                       const int* __restrict__ slots, const float* __restrict__ pin,
                       float* __restrict__ z, float* __restrict__ p_out,
                       float* __restrict__ sig, int first, int N) {
    __shared__ float red[TPB];
    int i = blockIdx.x * blockDim.x + threadIdx.x;
    float zv = 0.0f;
    if (i < N) {
        int c = cnt[i];
        if (c > KSLOT) c = KSLOT;
        const int* row = slots + (size_t)i * KSLOT;
        float q = 0.0f;
        for (int r = 0; r < c; r += 4) {          // row is 16B-aligned; reads
            int4 s4 = *(const int4*)(row + r);    // past c stay inside the row
            if (r + 0 < c) q += pin[s4.x];
            if (r + 1 < c) q += pin[s4.y];
            if (r + 2 < c) q += pin[s4.z];
            if (r + 3 < c) q += pin[s4.w];
        }
        float dv = dinvf[i];
        float zprev = first ? 1.0f : z[i];
        zv = dv * (q + dv * zprev);
        z[i] = zv;
        if (p_out) p_out[i] = dv * zv;
    }
    if (sig) {
        red[threadIdx.x] = zv;
        __syncthreads();
        for (int s = TPB / 2; s > 0; s >>= 1) {
            if (threadIdx.x < s) red[threadIdx.x] += red[threadIdx.x + s];
            __syncthreads();
        }
        if (threadIdx.x == 0) unsafeAtomicAdd(sig, red[0]);
    }
}

// Layer 3 fused with the X reduction: block b computes z3 for its 256 rows
// (same gather form, zprev = z2 in place, z3 store dropped — dead), then
// partials[b][0:128] = sum_{r in block} z3[r] * X[r][0:128].
__global__ void k_qfin3w(const float* __restrict__ dinvf, const int* __restrict__ cnt,
                         const int* __restrict__ slots, const float* __restrict__ pin,
                         const float* __restrict__ z, const float* __restrict__ x,
                         float* __restrict__ partials, int N) {
    __shared__ float zbuf[TPB];
    __shared__ float4 red4[TPB];
    int tid = threadIdx.x;
    int i = blockIdx.x * blockDim.x + tid;
    float zv = 0.0f;
    if (i < N) {
        int c = cnt[i];
        if (c > KSLOT) c = KSLOT;
        const int* row = slots + (size_t)i * KSLOT;
        float q = 0.0f;
        for (int r = 0; r < c; r += 4) {
            int4 s4 = *(const int4*)(row + r);
            if (r + 0 < c) q += pin[s4.x];
            if (r + 1 < c) q += pin[s4.y];
            if (r + 2 < c) q += pin[s4.z];
            if (r + 3 < c) q += pin[s4.w];
        }
        float dv = dinvf[i];
        zv = dv * (q + dv * z[i]);
    }
    zbuf[tid] = zv;
    __syncthreads();
    int base = blockIdx.x * TPB;
    int nrows = N - base; if (nrows > TPB) nrows = TPB;
    int c4 = (tid & 31) * 4;
    int rg = tid >> 5;                            // 8 row-groups
    float4 acc = make_float4(0.f, 0.f, 0.f, 0.f);
    for (int r = rg; r < nrows; r += 8) {
        float zr = zbuf[r];
        const float4 xv = *(const float4*)(x + (size_t)(base + r) * 128 + c4);
        acc.x += zr * xv.x; acc.y += zr * xv.y;
        acc.z += zr * xv.z; acc.w += zr * xv.w;
    }
    red4[tid] = acc;
    __syncthreads();
    if (tid < 32) {
        float4 a = red4[tid];
        #pragma unroll
        for (int g = 1; g < 8; ++g) {
            float4 b = red4[tid + 32 * g];
            a.x += b.x; a.y += b.y; a.z += b.z; a.w += b.w;
        }
        float* pp = partials + (size_t)blockIdx.x * 128 + c4;
        pp[0] = a.x; pp[1] = a.y; pp[2] = a.z; pp[3] = a.w;
    }
}

// 1024 threads: reduce partials -> u0, then 3-layer 128-wide chain.
__global__ __launch_bounds__(1024) void k_final(
        const float* __restrict__ partials, int nb,
        const float* __restrict__ Ws, const float* __restrict__ bs,
        const float* __restrict__ sig, float* __restrict__ out, int N) {
    __shared__ float uv[128];
    __shared__ float red[1024];
    int t = threadIdx.x;
    int j = t & 127, g = t >> 7;            // g in [0,8)
    float acc = 0.0f;
    for (int b = g; b < nb; b += 8) acc += partials[(size_t)b * 128 + j];
    red[t] = acc;
    __syncthreads();
    if (t < 128) {
        float s = 0.0f;
        #pragma unroll
        for (int gg = 0; gg < 8; ++gg) s += red[t + 128 * gg];
        uv[t] = s;
    }
    __syncthreads();
    float s1 = sig[0], s2 = sig[1];
    for (int l = 0; l < 3; ++l) {
        const float* W = Ws + (size_t)l * 16384;
        float a = 0.0f;
        #pragma unroll
        for (int kk = 0; kk < 16; ++kk) {
            int k = g * 16 + kk;
            a += uv[k] * W[k * 128 + j];
        }
        red[t] = a;
        __syncthreads();
        float nv = 0.0f;
        if (t < 128) {
            float s = 0.0f;
            #pragma unroll
            for (int gg = 0; gg < 8; ++gg) s += red[t + 128 * gg];
            float coef = (l == 0) ? s2 : (l == 1) ? s1 : (float)N;
            nv = s + coef * bs[l * 128 + t];
        }
        __syncthreads();
        if (t < 128) uv[t] = nv;
        __syncthreads();
    }
    if (t < 128) out[t] = uv[t] * (float)(1.0 / sqrt((double)N));
}

extern "C" void kernel_launch(void* const* d_in, const int* in_sizes, int n_in,
                              void* d_out, int out_size, void* d_ws, size_t ws_size,
                              hipStream_t stream) {
    const int*   ei = (const int*)d_in[0];
    const float* X  = (const float*)d_in[1];
    const float* Ws = (const float*)d_in[2];
    const float* bs = (const float*)d_in[3];
    float* out = (float*)d_out;

    int E = in_sizes[0] / 2;
    int N = in_sizes[1] / 128;
    const int* src = ei;
    const int* dst = ei + E;

    int gE = (E + TPB - 1) / TPB;
    int gN = (N + TPB - 1) / TPB;
    int NR = (N + RBINS - 1) / RBINS;       // 25 ranges @ N=100k
    int NH = NR * HCHUNKS;                  // 200 histogram blocks

    // layout (floats): [cnt N][sig 4][dinvf N][z N][pa N][pb N]
    //                  [partials gN*128][pdeg HCHUNKS*N][slots N*KSLOT]
    float* ws       = (float*)d_ws;
    int*   cnt      = (int*)ws;                  // [N] memset 0
    float* sig      = ws + N;                    // [4] memset 0
    float* dinvf    = ws + N + 4;                // [N] written by k_merge
    float* z        = ws + 2 * N + 4;            // [N] z1 -> z2 in place
    float* pa       = z + N;                     // [N] p1
    float* pb       = pa + N;                    // [N] p2
    float* partials = pb + N;                    // [gN*128]
    int*   pdeg     = (int*)(partials + (size_t)gN * 128);   // [HCHUNKS*N]
    size_t so = ((size_t)(5 * (size_t)N + 4) + (size_t)gN * 128
                 + (size_t)HCHUNKS * N + 3) & ~(size_t)3;
    int*   slots    = (int*)(ws + so);           // [N*KSLOT] (16B-aligned)

    hipMemsetAsync(d_ws, 0, (size_t)(N + 4) * sizeof(float), stream);

    k_hist <<<NH + gE, TPB, 0, stream>>>(src, dst, cnt, pdeg, slots, E, N, NH);
    k_merge<<<gN, TPB, 0, stream>>>(pdeg, dinvf, N);
    // layer 1: pin = dinvf (z0 = 1); sig[0] = sum z1
    k_qfin <<<gN, TPB, 0, stream>>>(dinvf, cnt, slots, dinvf, z, pa, &sig[0], 1, N);
    // layer 2: pin = p1, zprev = z1 in place; sig[1] = sum z2
    k_qfin <<<gN, TPB, 0, stream>>>(dinvf, cnt, slots, pa, z, pb, &sig[1], 0, N);
    // layer 3 fused with X reduction (z3 never materialized)
    k_qfin3w<<<gN, TPB, 0, stream>>>(dinvf, cnt, slots, pb, z, X, partials, N);
    k_final <<<1, 1024, 0, stream>>>(partials, gN, Ws, bs, sig, out, N);
}

// Round 3
// 195.402 us; speedup vs baseline: 2.0318x; 1.0126x over previous
//
#include <hip/hip_runtime.h>
#include <math.h>

// GCN is linear: out = (((z3^T X) W1 + s2 b1) W2 + s1 b2) W3 + N b3) / sqrt(N)
// z_{l+1} = M^T z_l via gather over slot entries keyed by src; p_l = dinv.*z_l.
// Inherited laws (r7-r15):
//   (1) non-returning random atomics ride free; RETURNING atomics are the
//       cost: 13.3 G/s measured alone (r15), 21 G/s only in the 50/50 mix
//   (2) same-address atomics ~13 ns each, serialized (<1k block-adds ok)
//   (3) in-kernel device-scope fences poison resident L2 -> kernel boundary
//       is the only cheap device-wide sync
//   (4) random 4B L2 gathers ~free   (5) ~3.5 us per dispatch boundary
//   (6) micro-restructurings of the latency-class kernels regress
// ROUND 16 (this session): zero global atomics + transposed slots.
//   a) k_hist2: NR x HCHUNKS LDS-histogram blocks ALSO emit per-edge rank
//      (LDS atomicAdd return) for src, and dst counts. No global atomics.
//   b) k_merge2: dinvf from dst-counts; exclusive chunk-prefix of src-counts
//      in place (base); cnt[i] = total.
//   c) k_scatter: pos = base[chunk][src] + rank[e]; plain random 4B store
//      into TRANSPOSED slots_t[pos*N + src]. Zero atomics.
//   d) qfin layers read slots_t coalesced (lane i, rank r -> slots_t[r*N+i])
//      instead of strided 256B rows of a 25.6MB array (cold-HBM latency).

#define TPB 256
#define KSLOT 64
#define RBINS 4096     // bins per histogram block -> 2x16KB LDS
#define HCHUNKS 8      // edge chunks

__device__ __forceinline__ float dinv_of(int degv) {
    return (float)(1.0 / sqrt((double)degv + 1.0));
}

// Block = (range r, chunk c): scan chunk c of (src,dst) once.
//   src in range: rank[e] = atomicAdd(&hs[s-lo],1)  (LDS returning atomic)
//   dst in range: atomicAdd(&hd[d-lo],1)
// Store per-chunk counts: pdeg_src[c][i], pdeg_dst[c][i]. No global atomics.
__global__ void k_hist2(const int* __restrict__ src, const int* __restrict__ dst,
                        int* __restrict__ pdeg_src, int* __restrict__ pdeg_dst,
                        int* __restrict__ rank, int E, int N, int EC) {
    __shared__ int hs[RBINS];
    __shared__ int hd[RBINS];
    int r = blockIdx.x / HCHUNKS;
    int c = blockIdx.x % HCHUNKS;
    int lo = r * RBINS;
    for (int k = threadIdx.x; k < RBINS; k += TPB) { hs[k] = 0; hd[k] = 0; }
    __syncthreads();
    int e0 = c * EC;
    int e1 = e0 + EC; if (e1 > E) e1 = E;
    if (e0 < e1) {
        int n4 = (e1 - e0) >> 2;
        const int4* ps = (const int4*)(src + e0);
        const int4* pd = (const int4*)(dst + e0);
        int j = threadIdx.x;
        for (; j + 3 * TPB < n4; j += 4 * TPB) {       // 8 loads in flight
            int4 sv[4], dv[4];
            #pragma unroll
            for (int u = 0; u < 4; ++u) { sv[u] = ps[j + u * TPB]; dv[u] = pd[j + u * TPB]; }
            #pragma unroll
            for (int u = 0; u < 4; ++u) {
                int eb = e0 + ((j + u * TPB) << 2);
                int a;
                a = sv[u].x - lo; if ((unsigned)a < RBINS) rank[eb + 0] = atomicAdd(&hs[a], 1);
                a = sv[u].y - lo; if ((unsigned)a < RBINS) rank[eb + 1] = atomicAdd(&hs[a], 1);
                a = sv[u].z - lo; if ((unsigned)a < RBINS) rank[eb + 2] = atomicAdd(&hs[a], 1);
                a = sv[u].w - lo; if ((unsigned)a < RBINS) rank[eb + 3] = atomicAdd(&hs[a], 1);
                a = dv[u].x - lo; if ((unsigned)a < RBINS) atomicAdd(&hd[a], 1);
                a = dv[u].y - lo; if ((unsigned)a < RBINS) atomicAdd(&hd[a], 1);
                a = dv[u].z - lo; if ((unsigned)a < RBINS) atomicAdd(&hd[a], 1);
                a = dv[u].w - lo; if ((unsigned)a < RBINS) atomicAdd(&hd[a], 1);
            }
        }
        for (; j < n4; j += TPB) {
            int4 sv = ps[j], dv = pd[j];
            int eb = e0 + (j << 2);
            int a;
            a = sv.x - lo; if ((unsigned)a < RBINS) rank[eb + 0] = atomicAdd(&hs[a], 1);
            a = sv.y - lo; if ((unsigned)a < RBINS) rank[eb + 1] = atomicAdd(&hs[a], 1);
            a = sv.z - lo; if ((unsigned)a < RBINS) rank[eb + 2] = atomicAdd(&hs[a], 1);
            a = sv.w - lo; if ((unsigned)a < RBINS) rank[eb + 3] = atomicAdd(&hs[a], 1);
            a = dv.x - lo; if ((unsigned)a < RBINS) atomicAdd(&hd[a], 1);
            a = dv.y - lo; if ((unsigned)a < RBINS) atomicAdd(&hd[a], 1);
            a = dv.z - lo; if ((unsigned)a < RBINS) atomicAdd(&hd[a], 1);
            a = dv.w - lo; if ((unsigned)a < RBINS) atomicAdd(&hd[a], 1);
        }
        for (int t = e0 + (n4 << 2) + threadIdx.x; t < e1; t += TPB) {
            int a = src[t] - lo; if ((unsigned)a < RBINS) rank[t] = atomicAdd(&hs[a], 1);
            a = dst[t] - lo;     if ((unsigned)a < RBINS) atomicAdd(&hd[a], 1);
        }
    }
    __syncthreads();
    for (int k = threadIdx.x; k < RBINS; k += TPB) {
        int g = lo + k;
        if (g < N) {
            pdeg_src[(size_t)c * N + g] = hs[k];
            pdeg_dst[(size_t)c * N + g] = hd[k];
        }
    }
}

// dinvf from dst-count sum; exclusive chunk-prefix of src-counts IN PLACE
// (pdeg_src becomes base); cnt[i] = total src count. All coalesced.
__global__ void k_merge2(int* __restrict__ pdeg_src, const int* __restrict__ pdeg_dst,
                         int* __restrict__ cnt, float* __restrict__ dinvf, int N) {
    int i = blockIdx.x * blockDim.x + threadIdx.x;
    if (i < N) {
        int sd = 0;
        #pragma unroll
        for (int c = 0; c < HCHUNKS; ++c) sd += pdeg_dst[(size_t)c * N + i];
        dinvf[i] = dinv_of(sd);
        int run = 0;
        #pragma unroll
        for (int c = 0; c < HCHUNKS; ++c) {
            int v = pdeg_src[(size_t)c * N + i];
            pdeg_src[(size_t)c * N + i] = run;
            run += v;
        }
        cnt[i] = run;
    }
}

// slots_t[pos*N + s] = d with pos = base[chunk(e)][s] + rank[e]. No atomics;
// coalesced reads + one random 4B gather (base) + one random 4B store.
__global__ void k_scatter(const int* __restrict__ src, const int* __restrict__ dst,
                          const int* __restrict__ rank, const int* __restrict__ base,
                          int* __restrict__ slots_t, int E, int N, int EC) {
    int e = blockIdx.x * blockDim.x + threadIdx.x;
    if (e < E) {
        int s = src[e], d = dst[e];
        int c = e / EC;
        int pos = base[(size_t)c * N + s] + rank[e];
        if (pos < KSLOT) slots_t[(size_t)pos * N + s] = d;
    }
}

// One propagation layer (1 thread/node), TRANSPOSED coalesced slot reads:
//   q      = sum_{r<cnt[i]} pin[slots_t[r*N+i]]   (layer 1: pin = dinvf)
//   z[i]   = dinv*(q + dinv*zprev)                (first => zprev=1, else z[i])
//   p_out  = dinv*z[i]  (if p_out)  ;  *sig += sum(z)  (if sig)
__global__ void k_qfin(const float* __restrict__ dinvf, const int* __restrict__ cnt,
                       const int* __restrict__ slots_t, const float* __restrict__ pin,
                       float* __restrict__ z, float* __restrict__ p_out,
                       float* __restrict__ sig, int first, int N) {
    __shared__ float red[TPB];
    int i = blockIdx.x * blockDim.x + threadIdx.x;
    float zv = 0.0f;
    if (i < N) {
        int c = cnt[i];
        if (c > KSLOT) c = KSLOT;
        float q = 0.0f;
        int r = 0;
        for (; r + 4 <= c; r += 4) {                  // 4 gathers in flight
            int j0 = slots_t[(size_t)(r + 0) * N + i];
            int j1 = slots_t[(size_t)(r + 1) * N + i];
            int j2 = slots_t[(size_t)(r + 2) * N + i];
            int j3 = slots_t[(size_t)(r + 3) * N + i];
            q += pin[j0] + pin[j1] + pin[j2] + pin[j3];
        }
        for (; r < c; ++r) q += pin[slots_t[(size_t)r * N + i]];
        float dv = dinvf[i];
        float zprev = first ? 1.0f : z[i];
        zv = dv * (q + dv * zprev);
        z[i] = zv;
        if (p_out) p_out[i] = dv * zv;
    }
    if (sig) {
        red[threadIdx.x] = zv;
        __syncthreads();
        for (int s = TPB / 2; s > 0; s >>= 1) {
            if (threadIdx.x < s) red[threadIdx.x] += red[threadIdx.x + s];
            __syncthreads();
        }
        if (threadIdx.x == 0) unsafeAtomicAdd(sig, red[0]);
    }
}

// Layer 3 fused with the X reduction: block b computes z3 for its 256 rows
// (transposed gather, zprev = z2 in place, z3 store dead), then
// partials[b][0:128] = sum_{r in block} z3[r] * X[r][0:128].
__global__ void k_qfin3w(const float* __restrict__ dinvf, const int* __restrict__ cnt,
                         const int* __restrict__ slots_t, const float* __restrict__ pin,
                         const float* __restrict__ z, const float* __restrict__ x,
                         float* __restrict__ partials, int N) {
    __shared__ float zbuf[TPB];
    __shared__ float4 red4[TPB];
    int tid = threadIdx.x;
    int i = blockIdx.x * blockDim.x + tid;
    float zv = 0.0f;
    if (i < N) {
        int c = cnt[i];
        if (c > KSLOT) c = KSLOT;
        float q = 0.0f;
        int r = 0;
        for (; r + 4 <= c; r += 4) {
            int j0 = slots_t[(size_t)(r + 0) * N + i];
            int j1 = slots_t[(size_t)(r + 1) * N + i];
            int j2 = slots_t[(size_t)(r + 2) * N + i];
            int j3 = slots_t[(size_t)(r + 3) * N + i];
            q += pin[j0] + pin[j1] + pin[j2] + pin[j3];
        }
        for (; r < c; ++r) q += pin[slots_t[(size_t)r * N + i]];
        float dv = dinvf[i];
        zv = dv * (q + dv * z[i]);
    }
    zbuf[tid] = zv;
    __syncthreads();
    int base = blockIdx.x * TPB;
    int nrows = N - base; if (nrows > TPB) nrows = TPB;
    int c4 = (tid & 31) * 4;
    int rg = tid >> 5;                            // 8 row-groups
    float4 acc = make_float4(0.f, 0.f, 0.f, 0.f);
    for (int r = rg; r < nrows; r += 8) {
        float zr = zbuf[r];
        const float4 xv = *(const float4*)(x + (size_t)(base + r) * 128 + c4);
        acc.x += zr * xv.x; acc.y += zr * xv.y;
        acc.z += zr * xv.z; acc.w += zr * xv.w;
    }
    red4[tid] = acc;
    __syncthreads();
    if (tid < 32) {
        float4 a = red4[tid];
        #pragma unroll
        for (int g = 1; g < 8; ++g) {
            float4 b = red4[tid + 32 * g];
            a.x += b.x; a.y += b.y; a.z += b.z; a.w += b.w;
        }
        float* pp = partials + (size_t)blockIdx.x * 128 + c4;
        pp[0] = a.x; pp[1] = a.y; pp[2] = a.z; pp[3] = a.w;
    }
}

// 1024 threads: reduce partials -> u0, then 3-layer 128-wide chain.
__global__ __launch_bounds__(1024) void k_final(
        const float* __restrict__ partials, int nb,
        const float* __restrict__ Ws, const float* __restrict__ bs,
        const float* __restrict__ sig, float* __restrict__ out, int N) {
    __shared__ float uv[128];
    __shared__ float red[1024];
    int t = threadIdx.x;
    int j = t & 127, g = t >> 7;            // g in [0,8)
    float acc = 0.0f;
    for (int b = g; b < nb; b += 8) acc += partials[(size_t)b * 128 + j];
    red[t] = acc;
    __syncthreads();
    if (t < 128) {
        float s = 0.0f;
        #pragma unroll
        for (int gg = 0; gg < 8; ++gg) s += red[t + 128 * gg];
        uv[t] = s;
    }
    __syncthreads();
    float s1 = sig[0], s2 = sig[1];
    for (int l = 0; l < 3; ++l) {
        const float* W = Ws + (size_t)l * 16384;
        float a = 0.0f;
        #pragma unroll
        for (int kk = 0; kk < 16; ++kk) {
            int k = g * 16 + kk;
            a += uv[k] * W[k * 128 + j];
        }
        red[t] = a;
        __syncthreads();
        float nv = 0.0f;
        if (t < 128) {
            float s = 0.0f;
            #pragma unroll
            for (int gg = 0; gg < 8; ++gg) s += red[t + 128 * gg];
            float coef = (l == 0) ? s2 : (l == 1) ? s1 : (float)N;
            nv = s + coef * bs[l * 128 + t];
        }
        __syncthreads();
        if (t < 128) uv[t] = nv;
        __syncthreads();
    }
    if (t < 128) out[t] = uv[t] * (float)(1.0 / sqrt((double)N));
}

extern "C" void kernel_launch(void* const* d_in, const int* in_sizes, int n_in,
                              void* d_out, int out_size, void* d_ws, size_t ws_size,
                              hipStream_t stream) {
    const int*   ei = (const int*)d_in[0];
    const float* X  = (const float*)d_in[1];
    const float* Ws = (const float*)d_in[2];
    const float* bs = (const float*)d_in[3];
    float* out = (float*)d_out;

    int E = in_sizes[0] / 2;
    int N = in_sizes[1] / 128;
    const int* src = ei;
    const int* dst = ei + E;

    int gE = (E + TPB - 1) / TPB;
    int gN = (N + TPB - 1) / TPB;
    int NR = (N + RBINS - 1) / RBINS;               // 25 ranges @ N=100k
    int EC = ((E + HCHUNKS - 1) / HCHUNKS + 3) & ~3; // 16B-aligned chunks

    // layout (floats): [sig 4][cnt N][dinvf N][z N][pa N][pb N]
    //   [partials gN*128][pdeg_src HC*N][pdeg_dst HC*N][rank E][slots_t K*N]
    float* ws       = (float*)d_ws;
    float* sig      = ws;                            // [4] memset 0
    int*   cnt      = (int*)(ws + 4);                // [N] by k_merge2
    float* dinvf    = ws + 4 + N;                    // [N] by k_merge2
    float* z        = ws + 4 + 2 * N;                // [N] z1 -> z2 in place
    float* pa       = z + N;                         // [N] p1
    float* pb       = pa + N;                        // [N] p2
    float* partials = pb + N;                        // [gN*128]
    int*   pdeg_src = (int*)(partials + (size_t)gN * 128);   // [HC*N] -> base
    int*   pdeg_dst = pdeg_src + (size_t)HCHUNKS * N;        // [HC*N]
    int*   rank     = pdeg_dst + (size_t)HCHUNKS * N;        // [E]
    int*   slots_t  = rank + E;                              // [KSLOT*N]

    hipMemsetAsync(d_ws, 0, 4 * sizeof(float), stream);

    k_hist2 <<<NR * HCHUNKS, TPB, 0, stream>>>(src, dst, pdeg_src, pdeg_dst,
                                               rank, E, N, EC);
    k_merge2<<<gN, TPB, 0, stream>>>(pdeg_src, pdeg_dst, cnt, dinvf, N);
    k_scatter<<<gE, TPB, 0, stream>>>(src, dst, rank, pdeg_src, slots_t, E, N, EC);
    // layer 1: pin = dinvf (z0 = 1); sig[0] = sum z1
    k_qfin <<<gN, TPB, 0, stream>>>(dinvf, cnt, slots_t, dinvf, z, pa, &sig[0], 1, N);
    // layer 2: pin = p1, zprev = z1 in place; sig[1] = sum z2
    k_qfin <<<gN, TPB, 0, stream>>>(dinvf, cnt, slots_t, pa, z, pb, &sig[1], 0, N);
    // layer 3 fused with X reduction (z3 never materialized)
    k_qfin3w<<<gN, TPB, 0, stream>>>(dinvf, cnt, slots_t, pb, z, X, partials, N);
    k_final <<<1, 1024, 0, stream>>>(partials, gN, Ws, bs, sig, out, N);
}